// Round 1
// 2903.572 us; speedup vs baseline: 1.0055x; 1.0055x over previous
//
#include <hip/hip_runtime.h>
#include <stdint.h>

#define D_DIM 2048
#define F_DIM 5632
#define E_NUM 8
#define N_TOK 8192
#define MAXSLOTS 17408      // 16384 + 8*128 worst-case padding
#define MAXTILES 136        // MAXSLOTS/128
#define FTILES 44           // 5632/128
#define DTILES 16           // 2048/128
#define WELEM 92274688      // 8*5632*2048

typedef __attribute__((ext_vector_type(4))) float f32x4;
typedef __attribute__((ext_vector_type(8))) short s16x8;

// ctrl block word indices (ints unless noted)
#define C_COUNT 0    // [8]
#define C_CURSOR 8   // [8]
#define C_POFF 16    // [9] padded row offsets
#define C_TOFF 25    // [9] tile offsets
#define C_TOTAL 34   // total tiles
#define C_SSUM 40    // [8] floats: softmax prob sums

__device__ __forceinline__ unsigned short f2bf(float f) {
  union { float f; unsigned u; } v; v.f = f;
  return (unsigned short)((v.u + 0x7FFFu + ((v.u >> 16) & 1u)) >> 16);  // RNE
}

__device__ __forceinline__ void load_lds16(const void* g, void* l) {
  __builtin_amdgcn_global_load_lds(
      reinterpret_cast<const __attribute__((address_space(1))) void*>(
          reinterpret_cast<uintptr_t>(g)),
      reinterpret_cast<__attribute__((address_space(3))) void*>(
          reinterpret_cast<uintptr_t>(l)),
      16, 0, 0);
}

__global__ __launch_bounds__(256) void k_init(int* ctrl, int* slot_token) {
  int id = blockIdx.x * 256 + threadIdx.x;
  if (id < MAXSLOTS) slot_token[id] = -1;
  if (id < 48) ctrl[id] = 0;  // counts, cursors, (junk), ssum floats (0 bits)
}

__global__ __launch_bounds__(256) void k_conv(const float* __restrict__ src,
                                              unsigned short* __restrict__ dst,
                                              int n4) {
  int stride = gridDim.x * 256;
  for (int i = blockIdx.x * 256 + threadIdx.x; i < n4; i += stride) {
    float4 v = ((const float4*)src)[i];
    ushort4 o;
    o.x = f2bf(v.x); o.y = f2bf(v.y); o.z = f2bf(v.z); o.w = f2bf(v.w);
    ((ushort4*)dst)[i] = o;
  }
}

// one wave per token: logits, softmax, top-2, aux stats
__global__ __launch_bounds__(256) void k_router(
    const float* __restrict__ x, const float* __restrict__ rw,
    int* __restrict__ topk_id, float* __restrict__ topk_w, int* ctrl) {
  __shared__ float bsum[E_NUM];
  __shared__ int bcnt[E_NUM];
  int tid = threadIdx.x;
  if (tid < E_NUM) { bsum[tid] = 0.f; bcnt[tid] = 0; }
  __syncthreads();
  int wave = tid >> 6, lane = tid & 63;
  int token = blockIdx.x * 4 + wave;
  const float4* xv = (const float4*)(x + (size_t)token * D_DIM);
  const float4* wv = (const float4*)rw;
  float acc[E_NUM];
#pragma unroll
  for (int e = 0; e < E_NUM; ++e) acc[e] = 0.f;
  for (int i = lane; i < D_DIM / 4; i += 64) {
    float4 xd = xv[i];
#pragma unroll
    for (int e = 0; e < E_NUM; ++e) {
      float4 wd = wv[e * (D_DIM / 4) + i];
      acc[e] += xd.x * wd.x + xd.y * wd.y + xd.z * wd.z + xd.w * wd.w;
    }
  }
#pragma unroll
  for (int e = 0; e < E_NUM; ++e)
    for (int off = 32; off > 0; off >>= 1) acc[e] += __shfl_down(acc[e], off);
  if (lane == 0) {
    float m = acc[0];
    for (int e = 1; e < E_NUM; ++e) m = fmaxf(m, acc[e]);
    float s[E_NUM], sum = 0.f;
    for (int e = 0; e < E_NUM; ++e) { s[e] = __expf(acc[e] - m); sum += s[e]; }
    float inv = 1.f / sum;
    // top-2 on logits (monotone with softmax); strict > keeps lowest index on tie
    int e1 = 0; float v1 = acc[0];
    for (int e = 1; e < E_NUM; ++e) if (acc[e] > v1) { v1 = acc[e]; e1 = e; }
    int e2 = (e1 == 0) ? 1 : 0; float v2 = acc[e2];
    for (int e = 0; e < E_NUM; ++e)
      if (e != e1 && acc[e] > v2) { v2 = acc[e]; e2 = e; }
    float p1 = s[e1], p2 = s[e2], wsum = p1 + p2;
    topk_id[token * 2] = e1; topk_id[token * 2 + 1] = e2;
    topk_w[token * 2] = p1 / wsum; topk_w[token * 2 + 1] = p2 / wsum;
    for (int e = 0; e < E_NUM; ++e) atomicAdd(&bsum[e], s[e] * inv);
    atomicAdd(&bcnt[e1], 1); atomicAdd(&bcnt[e2], 1);
  }
  __syncthreads();
  if (tid < E_NUM) {
    atomicAdd((float*)ctrl + C_SSUM + tid, bsum[tid]);
    atomicAdd(ctrl + C_COUNT + tid, bcnt[tid]);
  }
}

__global__ void k_offsets(int* ctrl, float* aux_out) {
  if (threadIdx.x == 0) {
    int po = 0;
    ctrl[C_POFF] = 0; ctrl[C_TOFF] = 0;
    float aux = 0.f;
    for (int e = 0; e < E_NUM; ++e) {
      int c = ctrl[C_COUNT + e];
      float probs = ((float*)ctrl)[C_SSUM + e] / (float)N_TOK;
      aux += probs * ((float)c / (float)N_TOK);
      po += ((c + 127) >> 7) << 7;
      ctrl[C_POFF + e + 1] = po;
      ctrl[C_TOFF + e + 1] = po >> 7;
    }
    ctrl[C_TOTAL] = po >> 7;
    *aux_out = (float)E_NUM * aux;
  }
}

__global__ __launch_bounds__(256) void k_scatter(
    const int* __restrict__ topk_id, int* ctrl,
    int* __restrict__ slot_token, int* __restrict__ token_slot) {
  int id = blockIdx.x * 256 + threadIdx.x;
  if (id >= N_TOK * 2) return;
  int e = topk_id[id];
  int r = atomicAdd(&ctrl[C_CURSOR + e], 1);
  int slot = ctrl[C_POFF + e] + r;
  slot_token[slot] = id >> 1;
  token_slot[id] = slot;
}

__global__ __launch_bounds__(256) void k_gather(
    const float* __restrict__ x, const int* __restrict__ slot_token,
    unsigned short* __restrict__ xg) {
  int row = blockIdx.x;
  int tok = slot_token[row];
  ushort4* dst = (ushort4*)(xg + (size_t)row * D_DIM);
  if (tok < 0) {
    ushort4 z; z.x = z.y = z.z = z.w = 0;
    for (int i = threadIdx.x; i < D_DIM / 4; i += 256) dst[i] = z;
  } else {
    const float4* src = (const float4*)(x + (size_t)tok * D_DIM);
    for (int i = threadIdx.x; i < D_DIM / 4; i += 256) {
      float4 v = src[i];
      ushort4 o;
      o.x = f2bf(v.x); o.y = f2bf(v.y); o.z = f2bf(v.z); o.w = f2bf(v.w);
      dst[i] = o;
    }
  }
}

// fused gate+up grouped GEMM + SwiGLU epilogue. 128x128 tile, BK=32, 4 waves.
// LDS tile [128][32] ushort; 16B slot s of row r holds global slot s^((r>>1)&3)
// (XOR swizzle, rule: linear gload_lds dest + pre-swizzled SOURCE + swizzled READ).
// This turns the 8-way quarter-wave bank conflict on ds_read_b128 into 2-way (free).
__global__ __launch_bounds__(256, 2) void k_ffn1(
    const unsigned short* __restrict__ xg, const unsigned short* __restrict__ wg,
    const unsigned short* __restrict__ wu, unsigned short* __restrict__ h,
    const int* __restrict__ ctrl) {
  __shared__ unsigned short sm[3 * 128 * 32];
  int tm = blockIdx.x;
  if (tm >= ctrl[C_TOTAL]) return;
  int tn = blockIdx.y;
  int e = 0;
  while (ctrl[C_TOFF + e + 1] <= tm) ++e;
  const unsigned short* A = xg + (size_t)tm * 128 * D_DIM;
  const unsigned short* Bg = wg + ((size_t)e * F_DIM + (size_t)tn * 128) * D_DIM;
  const unsigned short* Bu = wu + ((size_t)e * F_DIM + (size_t)tn * 128) * D_DIM;
  unsigned short* As = sm;
  unsigned short* Bgs = sm + 4096;
  unsigned short* Bus = sm + 8192;
  int tid = threadIdx.x;
  int lane = tid & 63, w = tid >> 6;
  int wm = w & 1, wn = w >> 1;
  int quad = lane >> 4, l16 = lane & 15;
  // swizzled read slot (ushort offset): same for all mi/ni since row bits 1-2 come from l16
  int sq8 = (quad ^ ((l16 >> 1) & 3)) << 3;
  f32x4 accg[4][4], accu[4][4];
#pragma unroll
  for (int mi = 0; mi < 4; ++mi)
#pragma unroll
    for (int ni = 0; ni < 4; ++ni)
#pragma unroll
      for (int r = 0; r < 4; ++r) { accg[mi][ni][r] = 0.f; accu[mi][ni][r] = 0.f; }

  for (int k0 = 0; k0 < D_DIM; k0 += 32) {
#pragma unroll
    for (int i = 0; i < 2; ++i) {
      int li = i * 256 + tid;
      int r = li >> 2;
      int c = ((li & 3) ^ ((r >> 1) & 3)) << 3;  // pre-swizzled global source slot
      int lbase = (i * 256 + w * 64) << 3;  // ushort elems, wave-uniform (linear dest)
      load_lds16(A + (size_t)r * D_DIM + k0 + c, As + lbase);
      load_lds16(Bg + (size_t)r * D_DIM + k0 + c, Bgs + lbase);
      load_lds16(Bu + (size_t)r * D_DIM + k0 + c, Bus + lbase);
    }
    __syncthreads();  // drains vmcnt before barrier
    s16x8 a[4], bg[4], bu[4];
#pragma unroll
    for (int mi = 0; mi < 4; ++mi)
      a[mi] = *(const s16x8*)(As + (wm * 64 + mi * 16 + l16) * 32 + sq8);
#pragma unroll
    for (int ni = 0; ni < 4; ++ni) {
      bg[ni] = *(const s16x8*)(Bgs + (wn * 64 + ni * 16 + l16) * 32 + sq8);
      bu[ni] = *(const s16x8*)(Bus + (wn * 64 + ni * 16 + l16) * 32 + sq8);
    }
#pragma unroll
    for (int mi = 0; mi < 4; ++mi)
#pragma unroll
      for (int ni = 0; ni < 4; ++ni) {
        accg[mi][ni] = __builtin_amdgcn_mfma_f32_16x16x32_bf16(a[mi], bg[ni], accg[mi][ni], 0, 0, 0);
        accu[mi][ni] = __builtin_amdgcn_mfma_f32_16x16x32_bf16(a[mi], bu[ni], accu[mi][ni], 0, 0, 0);
      }
    __syncthreads();
  }
  int row0 = tm * 128 + wm * 64;
  int col0 = tn * 128 + wn * 64;
#pragma unroll
  for (int mi = 0; mi < 4; ++mi)
#pragma unroll
    for (int ni = 0; ni < 4; ++ni)
#pragma unroll
      for (int r = 0; r < 4; ++r) {
        float g = accg[mi][ni][r];
        float u = accu[mi][ni][r];
        float hv = g / (1.f + __expf(-g)) * u;  // silu(g)*u
        int row = row0 + mi * 16 + quad * 4 + r;
        int col = col0 + ni * 16 + l16;
        h[(size_t)row * F_DIM + col] = f2bf(hv);
      }
}

// down grouped GEMM: y[slot,d] = h[slot,:] @ wd[e][d,:]
// Same XOR swizzle as k_ffn1.
__global__ __launch_bounds__(256, 2) void k_ffn2(
    const unsigned short* __restrict__ h, const unsigned short* __restrict__ wd,
    float* __restrict__ y, const int* __restrict__ ctrl) {
  __shared__ unsigned short sm[2 * 128 * 32];
  int tm = blockIdx.x;
  if (tm >= ctrl[C_TOTAL]) return;
  int tn = blockIdx.y;
  int e = 0;
  while (ctrl[C_TOFF + e + 1] <= tm) ++e;
  const unsigned short* A = h + (size_t)tm * 128 * F_DIM;
  const unsigned short* B = wd + ((size_t)e * D_DIM + (size_t)tn * 128) * F_DIM;
  unsigned short* As = sm;
  unsigned short* Bs = sm + 4096;
  int tid = threadIdx.x;
  int lane = tid & 63, w = tid >> 6;
  int wm = w & 1, wn = w >> 1;
  int quad = lane >> 4, l16 = lane & 15;
  int sq8 = (quad ^ ((l16 >> 1) & 3)) << 3;
  f32x4 acc[4][4];
#pragma unroll
  for (int mi = 0; mi < 4; ++mi)
#pragma unroll
    for (int ni = 0; ni < 4; ++ni)
#pragma unroll
      for (int r = 0; r < 4; ++r) acc[mi][ni][r] = 0.f;

  for (int k0 = 0; k0 < F_DIM; k0 += 32) {
#pragma unroll
    for (int i = 0; i < 2; ++i) {
      int li = i * 256 + tid;
      int r = li >> 2;
      int c = ((li & 3) ^ ((r >> 1) & 3)) << 3;
      int lbase = (i * 256 + w * 64) << 3;
      load_lds16(A + (size_t)r * F_DIM + k0 + c, As + lbase);
      load_lds16(B + (size_t)r * F_DIM + k0 + c, Bs + lbase);
    }
    __syncthreads();
    s16x8 a[4], b[4];
#pragma unroll
    for (int mi = 0; mi < 4; ++mi)
      a[mi] = *(const s16x8*)(As + (wm * 64 + mi * 16 + l16) * 32 + sq8);
#pragma unroll
    for (int ni = 0; ni < 4; ++ni)
      b[ni] = *(const s16x8*)(Bs + (wn * 64 + ni * 16 + l16) * 32 + sq8);
#pragma unroll
    for (int mi = 0; mi < 4; ++mi)
#pragma unroll
      for (int ni = 0; ni < 4; ++ni)
        acc[mi][ni] = __builtin_amdgcn_mfma_f32_16x16x32_bf16(a[mi], b[ni], acc[mi][ni], 0, 0, 0);
    __syncthreads();
  }
  int row0 = tm * 128 + wm * 64;
  int col0 = tn * 128 + wn * 64;
#pragma unroll
  for (int mi = 0; mi < 4; ++mi)
#pragma unroll
    for (int ni = 0; ni < 4; ++ni)
#pragma unroll
      for (int r = 0; r < 4; ++r) {
        int row = row0 + mi * 16 + quad * 4 + r;
        int col = col0 + ni * 16 + l16;
        y[(size_t)row * D_DIM + col] = acc[mi][ni][r];
      }
}

__global__ __launch_bounds__(256) void k_combine(
    const float* __restrict__ y, const int* __restrict__ token_slot,
    const float* __restrict__ topk_w, float* __restrict__ out) {
  int gid = blockIdx.x * 256 + threadIdx.x;  // one float4 per thread
  int n = gid >> 9, c = gid & 511;           // 512 float4 per row
  int s0 = token_slot[n * 2], s1 = token_slot[n * 2 + 1];
  float w0 = topk_w[n * 2], w1 = topk_w[n * 2 + 1];
  float4 a = ((const float4*)(y + (size_t)s0 * D_DIM))[c];
  float4 b = ((const float4*)(y + (size_t)s1 * D_DIM))[c];
  float4 o;
  o.x = w0 * a.x + w1 * b.x;
  o.y = w0 * a.y + w1 * b.y;
  o.z = w0 * a.z + w1 * b.z;
  o.w = w0 * a.w + w1 * b.w;
  ((float4*)(out + (size_t)n * D_DIM))[c] = o;
}

extern "C" void kernel_launch(void* const* d_in, const int* in_sizes, int n_in,
                              void* d_out, int out_size, void* d_ws, size_t ws_size,
                              hipStream_t stream) {
  const float* x  = (const float*)d_in[0];
  const float* rw = (const float*)d_in[1];
  const float* gw = (const float*)d_in[2];
  const float* uw = (const float*)d_in[3];
  const float* dw = (const float*)d_in[4];
  float* out = (float*)d_out;
  char* ws = (char*)d_ws;

  // workspace layout
  size_t off = 0;
  int* ctrl = (int*)(ws + off); off += 256;
  int* topk_id = (int*)(ws + off); off += (size_t)N_TOK * 2 * 4;
  float* topk_w = (float*)(ws + off); off += (size_t)N_TOK * 2 * 4;
  int* slot_token = (int*)(ws + off); off += (size_t)MAXSLOTS * 4;
  int* token_slot = (int*)(ws + off); off += (size_t)N_TOK * 2 * 4;
  off = (off + 255) & ~(size_t)255;
  unsigned short* xg = (unsigned short*)(ws + off); off += (size_t)MAXSLOTS * D_DIM * 2;
  unsigned short* hb = (unsigned short*)(ws + off); off += (size_t)MAXSLOTS * F_DIM * 2;
  float* y = (float*)(ws + off); off += (size_t)MAXSLOTS * D_DIM * 4;
  unsigned short* wgb = (unsigned short*)(ws + off); off += (size_t)WELEM * 2;
  unsigned short* wub = (unsigned short*)(ws + off); off += (size_t)WELEM * 2;
  unsigned short* wdb = (unsigned short*)(ws + off); off += (size_t)WELEM * 2;

  k_init<<<68, 256, 0, stream>>>(ctrl, slot_token);
  k_conv<<<8192, 256, 0, stream>>>(gw, wgb, WELEM / 4);
  k_conv<<<8192, 256, 0, stream>>>(uw, wub, WELEM / 4);
  k_conv<<<8192, 256, 0, stream>>>(dw, wdb, WELEM / 4);
  k_router<<<N_TOK / 4, 256, 0, stream>>>(x, rw, topk_id, topk_w, ctrl);
  k_offsets<<<1, 64, 0, stream>>>(ctrl, out + (size_t)N_TOK * D_DIM);
  k_scatter<<<N_TOK * 2 / 256, 256, 0, stream>>>(topk_id, ctrl, slot_token, token_slot);
  k_gather<<<MAXSLOTS, 256, 0, stream>>>(x, slot_token, xg);
  k_ffn1<<<dim3(MAXTILES, FTILES), 256, 0, stream>>>(xg, wgb, wub, hb, ctrl);
  k_ffn2<<<dim3(MAXTILES, DTILES), 256, 0, stream>>>(hb, wdb, y, ctrl);
  k_combine<<<N_TOK * D_DIM / 4 / 256, 256, 0, stream>>>(y, token_slot, topk_w, out);
}